// Round 4
// baseline (175.279 us; speedup 1.0000x reference)
//
#include <hip/hip_runtime.h>
#include <cfloat>

// Problem constants: M=N=64 grid, DIM=512, B=4096, SIGMA=32
#define DIMK 512
#define MN   4096
#define BATCH 4096
#define BK 32
#define NCHUNK 64   // per-row argmin partials: 64 chunks of 64 cols

typedef _Float16 half8_t __attribute__((ext_vector_type(8)));
typedef _Float16 half4_t __attribute__((ext_vector_type(4)));
typedef float f32x4 __attribute__((ext_vector_type(4)));

// async global->LDS, 16B per lane; LDS dest is wave-uniform base + lane*16
#define GLD16(gp, lp) __builtin_amdgcn_global_load_lds( \
    (const __attribute__((address_space(1))) void*)(gp), \
    (__attribute__((address_space(3))) void*)(lp), 16, 0, 0)

// ---------------------------------------------------------------------------
// fp32 -> (hi, mid) f16 split: a = hi + mid + O(2^-22 |a|).
// Blocks < 2048 convert X; blocks >= 2048 convert W AND compute w2 row sums
// (each block covers exactly 2 rows of 512).
// ---------------------------------------------------------------------------
__global__ __launch_bounds__(256) void convert_kernel(
        const float* __restrict__ X, const float* __restrict__ W,
        _Float16* __restrict__ Xhi, _Float16* __restrict__ Xmi,
        _Float16* __restrict__ Whi, _Float16* __restrict__ Wmi,
        float* __restrict__ w2) {
    const int blk = blockIdx.x;
    const int t   = threadIdx.x;
    const bool isW = blk >= 2048;
    const float* src = isW ? W : X;
    _Float16* hi  = isW ? Whi : Xhi;
    _Float16* mid = isW ? Wmi : Xmi;
    const size_t base = (size_t)(isW ? blk - 2048 : blk) * 1024;
    const size_t idx  = base + (size_t)t * 4;
    float4 v = *(const float4*)(src + idx);
    _Float16 h0 = (_Float16)v.x, h1 = (_Float16)v.y,
             h2 = (_Float16)v.z, h3 = (_Float16)v.w;
    half4_t hv = {h0, h1, h2, h3};
    half4_t mv = {(_Float16)(v.x - (float)h0), (_Float16)(v.y - (float)h1),
                  (_Float16)(v.z - (float)h2), (_Float16)(v.w - (float)h3)};
    *(half4_t*)(hi + idx) = hv;
    *(half4_t*)(mid + idx) = mv;
    if (isW) {
        __shared__ float ws[4];
        float s = v.x*v.x + v.y*v.y + v.z*v.z + v.w*v.w;
        int lane = t & 63;
#pragma unroll
        for (int o = 32; o > 0; o >>= 1) s += __shfl_down(s, o);
        if (lane == 0) ws[t >> 6] = s;
        __syncthreads();
        size_t row = base >> 9;          // (blk-2048)*2
        if (t == 0)   w2[row]     = ws[0] + ws[1];
        if (t == 128) w2[row + 1] = ws[2] + ws[3];
    }
}

// ---------------------------------------------------------------------------
// MFMA score kernel: s[b,k] = w2[k] - 2*dot(X[b],W[k]) via 3-product f16 split.
// 128x128 tile, BK=32, SINGLE 32KB LDS buffer, 2 barriers/iter.
// Latency hiding comes from 3 independent blocks/CU (launch_bounds(256,3)):
// their barrier drains stagger against each other's MFMA phases (m97/m114).
// ---------------------------------------------------------------------------
__global__ __launch_bounds__(256, 3) void score_kernel(
        const _Float16* __restrict__ Xhi, const _Float16* __restrict__ Xmi,
        const _Float16* __restrict__ Whi, const _Float16* __restrict__ Wmi,
        const float* __restrict__ w2,
        float* __restrict__ pval, int* __restrict__ pidx) {
    __shared__ __align__(16) _Float16 lds[16384];   // 32 KB: Ah|Am|Bh|Bm
    _Float16* sAh = lds;
    _Float16* sAm = lds + 4096;
    _Float16* sBh = lds + 8192;
    _Float16* sBm = lds + 12288;

    const int t    = threadIdx.x;
    const int lane = t & 63;
    const int w    = t >> 6;        // wave 0..3
    const int wm   = w >> 1;        // wave m-half
    const int wn   = w & 1;         // wave n-half
    const int m0   = blockIdx.y * 128;
    const int n0   = blockIdx.x * 128;

    f32x4 acc[4][4];
#pragma unroll
    for (int i = 0; i < 4; i++)
#pragma unroll
        for (int j = 0; j < 4; j++) acc[i][j] = (f32x4){0.f, 0.f, 0.f, 0.f};

    // staging: wave w loads 16-row blocks (2w, 2w+1) of each of the 4 arrays.
    // within a 1KB block: lane l -> row (l&15), k-octet (l>>4).
    const int r16 = lane & 15;
    const int kg  = lane >> 4;
    const int b0  = 2 * w, b1 = 2 * w + 1;
    const size_t ko = (size_t)kg * 8;
    const _Float16* gAh0 = Xhi + (size_t)(m0 + b0 * 16 + r16) * DIMK + ko;
    const _Float16* gAh1 = Xhi + (size_t)(m0 + b1 * 16 + r16) * DIMK + ko;
    const _Float16* gAm0 = Xmi + (size_t)(m0 + b0 * 16 + r16) * DIMK + ko;
    const _Float16* gAm1 = Xmi + (size_t)(m0 + b1 * 16 + r16) * DIMK + ko;
    const _Float16* gBh0 = Whi + (size_t)(n0 + b0 * 16 + r16) * DIMK + ko;
    const _Float16* gBh1 = Whi + (size_t)(n0 + b1 * 16 + r16) * DIMK + ko;
    const _Float16* gBm0 = Wmi + (size_t)(n0 + b0 * 16 + r16) * DIMK + ko;
    const _Float16* gBm1 = Wmi + (size_t)(n0 + b1 * 16 + r16) * DIMK + ko;
    _Float16* dAh0 = sAh + b0 * 512;  _Float16* dAh1 = sAh + b1 * 512;
    _Float16* dAm0 = sAm + b0 * 512;  _Float16* dAm1 = sAm + b1 * 512;
    _Float16* dBh0 = sBh + b0 * 512;  _Float16* dBh1 = sBh + b1 * 512;
    _Float16* dBm0 = sBm + b0 * 512;  _Float16* dBm1 = sBm + b1 * 512;

    for (int k0 = 0; k0 < DIMK; k0 += BK) {
        __syncthreads();                 // previous iter's frag reads complete
        GLD16(gAh0 + k0, dAh0);
        GLD16(gAh1 + k0, dAh1);
        GLD16(gBh0 + k0, dBh0);
        GLD16(gBh1 + k0, dBh1);
        GLD16(gAm0 + k0, dAm0);
        GLD16(gAm1 + k0, dAm1);
        GLD16(gBm0 + k0, dBm0);
        GLD16(gBm1 + k0, dBm1);
        __syncthreads();                 // drains vmcnt (global_load_lds)

        half8_t ah[4], am[4], bh[4], bm[4];
#pragma unroll
        for (int i = 0; i < 4; i++) {
            ah[i] = *(const half8_t*)(sAh + (wm * 4 + i) * 512 + lane * 8);
            am[i] = *(const half8_t*)(sAm + (wm * 4 + i) * 512 + lane * 8);
            bh[i] = *(const half8_t*)(sBh + (wn * 4 + i) * 512 + lane * 8);
            bm[i] = *(const half8_t*)(sBm + (wn * 4 + i) * 512 + lane * 8);
        }
#pragma unroll
        for (int i = 0; i < 4; i++)
#pragma unroll
            for (int j = 0; j < 4; j++) {
                acc[i][j] = __builtin_amdgcn_mfma_f32_16x16x32_f16(am[i], bh[j], acc[i][j], 0, 0, 0);
                acc[i][j] = __builtin_amdgcn_mfma_f32_16x16x32_f16(ah[i], bm[j], acc[i][j], 0, 0, 0);
                acc[i][j] = __builtin_amdgcn_mfma_f32_16x16x32_f16(ah[i], bh[j], acc[i][j], 0, 0, 0);
            }
    }

    // ---- epilogue: per-row argmin over this wave's 64 cols ----
    // D layout: col = lane&15, row = (lane>>4)*4 + v   (m89/m91 verified)
    const int q  = lane >> 4;
    const int cl = lane & 15;
    float w2v[4];
    int   ncol[4];
#pragma unroll
    for (int j = 0; j < 4; j++) {
        ncol[j] = n0 + wn * 64 + j * 16 + cl;
        w2v[j]  = w2[ncol[j]];
    }
#pragma unroll
    for (int i = 0; i < 4; i++)
#pragma unroll
        for (int v = 0; v < 4; v++) {
            float bv = FLT_MAX;
            int   bi = 0x7FFFFFFF;
#pragma unroll
            for (int j = 0; j < 4; j++) {        // j ascending -> ties keep lower n
                float s = w2v[j] - 2.0f * acc[i][j][v];
                if (s < bv) { bv = s; bi = ncol[j]; }
            }
#pragma unroll
            for (int mask = 1; mask <= 8; mask <<= 1) {   // reduce over 16 col-lanes
                float ov = __shfl_xor(bv, mask);
                int   oi = __shfl_xor(bi, mask);
                if (ov < bv || (ov == bv && oi < bi)) { bv = ov; bi = oi; }
            }
            if (cl == 0) {
                int m = m0 + wm * 64 + i * 16 + q * 4 + v;
                int chunk = blockIdx.x * 2 + wn;
                pval[(size_t)m * NCHUNK + chunk] = bv;
                pidx[(size_t)m * NCHUNK + chunk] = bi;
            }
        }
}

// ---------------------------------------------------------------------------
// Final: reduce 64 partials/row -> BMU, separable Gaussian, write 4096 floats.
// ---------------------------------------------------------------------------
__global__ __launch_bounds__(256) void epilogue_kernel(
        const float* __restrict__ pval, const int* __restrict__ pidx,
        const int* __restrict__ decay_p, const int* __restrict__ it_p,
        float* __restrict__ out) {
    __shared__ float er[64];
    __shared__ float ec[64];
    __shared__ int   s_idx;
    const int b = blockIdx.x;
    const int t = threadIdx.x;

    if (t < 64) {
        float v  = pval[(size_t)b * NCHUNK + t];
        int   ii = pidx[(size_t)b * NCHUNK + t];
#pragma unroll
        for (int mask = 1; mask <= 32; mask <<= 1) {
            float ov = __shfl_xor(v, mask);
            int   oi = __shfl_xor(ii, mask);
            if (ov < v || (ov == v && oi < ii)) { v = ov; ii = oi; }
        }
        if (t == 0) s_idx = ii;
    }
    __syncthreads();
    const int r = s_idx >> 6;
    const int c = s_idx & 63;
    const float lr  = expf(-(float)(*it_p) / (float)(*decay_p));
    const float so  = 32.0f * lr;          // SIGMA = 32
    const float inv = 1.0f / (so * so);
    if (t < 64) {
        float d = (float)(t - r);
        er[t] = expf(-d * d * inv);
    } else if (t < 128) {
        int j = t - 64;
        float d = (float)(j - c);
        ec[j] = expf(-d * d * inv);
    }
    __syncthreads();
    float4* out4 = (float4*)(out + (size_t)b * 4096);
#pragma unroll
    for (int qq = 0; qq < 4; qq++) {
        int f  = t + 256 * qq;
        int i  = f >> 4;
        int j0 = (f & 15) * 4;
        float e = er[i];
        out4[f] = make_float4(e * ec[j0], e * ec[j0 + 1],
                              e * ec[j0 + 2], e * ec[j0 + 3]);
    }
}

// ---------------------------------------------------------------------------
extern "C" void kernel_launch(void* const* d_in, const int* in_sizes, int n_in,
                              void* d_out, int out_size, void* d_ws, size_t ws_size,
                              hipStream_t stream) {
    const float* X       = (const float*)d_in[0];   // [4096,512]
    const float* W       = (const float*)d_in[1];   // [4096,512]
    const int*   decay_p = (const int*)d_in[3];
    const int*   it_p    = (const int*)d_in[4];
    float* out = (float*)d_out;

    // ws: Xhi|Xmi|Whi|Wmi (4MB each f16) | w2 16KB | pval 1MB | pidx 1MB
    _Float16* Xhi = (_Float16*)d_ws;
    _Float16* Xmi = Xhi + (size_t)BATCH * DIMK;
    _Float16* Whi = Xmi + (size_t)BATCH * DIMK;
    _Float16* Wmi = Whi + (size_t)MN * DIMK;
    float*    w2  = (float*)(Wmi + (size_t)MN * DIMK);
    float*    pval = w2 + MN;
    int*      pidx = (int*)(pval + (size_t)BATCH * NCHUNK);

    convert_kernel<<<4096, 256, 0, stream>>>(X, W, Xhi, Xmi, Whi, Wmi, w2);
    score_kernel<<<dim3(32, 32), 256, 0, stream>>>(Xhi, Xmi, Whi, Wmi, w2, pval, pidx);
    epilogue_kernel<<<BATCH, 256, 0, stream>>>(pval, pidx, decay_p, it_p, out);
}